// Round 8
// baseline (76.227 us; speedup 1.0000x reference)
//
#include <hip/hip_runtime.h>
#include <hip/hip_fp16.h>
#include <math.h>

#define RES 256
#define TPAD 364              // padded texture dim: image coords -53..310
#define N_ANGLES 256
#define NA2 129               // paired angle slots: i and 256-i
#define BATCH 8
#define TEXB 32               // texel bytes: 8 fp16 normal + 8 fp16 x-flipped
#define ROWB (TPAD * TEXB)    // 11648

typedef _Float16 h2 __attribute__((ext_vector_type(2)));
__device__ inline h2 u2h(unsigned u) { return __builtin_bit_cast(h2, u); }

// Texel (32B): words 0-3 = {img_b}, words 4-7 = {img_b x-flipped}, fp16 pairs.
// TP = normal orientation, TPT = transposed. Zero outside image.
__global__ void prep_pack(const float* __restrict__ imgs,
                          unsigned int* __restrict__ TPw,
                          unsigned int* __restrict__ TPTw) {
    int idx = blockIdx.x * blockDim.x + threadIdx.x;
    const int total = 2 * TPAD * TPAD * 8;      // orient x pixel x word
    if (idx >= total) return;
    int word   = idx & 7;
    int px     = (idx >> 3) % (TPAD * TPAD);
    int orient = (idx >> 3) / (TPAD * TPAD);
    int side = word >> 2, pair = word & 3;
    int ct = px % TPAD, rt = px / TPAD;
    int ri = rt - 53, ci = ct - 53;
    int row, col;
    if (orient == 0) { row = ri; col = side ? (255 - ci) : ci; }
    else             { row = ci; col = side ? (255 - ri) : ri; }
    float v0 = 0.0f, v1 = 0.0f;
    if ((unsigned)row < RES && (unsigned)col < RES) {
        const float* p = imgs + ((size_t)(pair * 2) * RES + row) * RES + col;
        v0 = p[0];
        v1 = p[RES * RES];
    }
    __half2 h = __halves2half2(__float2half_rn(v0), __float2half_rn(v1));
    (orient ? TPTw : TPw)[(size_t)px * 8 + word] =
        *reinterpret_cast<unsigned int*>(&h);
}

// 1-wave blocks: lane = tap(2b) | tpar(1b) | sl(3b); grid (129 ang, 32 sblk, 2 z).
// Each lane-step: one tap for angle i (norm half) AND angle 256-i (flip half).
__global__ __launch_bounds__(64) void radon_kernel(
        const char* __restrict__ TP,
        const char* __restrict__ TPT,
        const float* __restrict__ angles,
        __half* __restrict__ part) {
    const int tid  = threadIdx.x;
    const int tap  = tid & 3;
    const int tpar = (tid >> 2) & 1;
    const int s    = blockIdx.y * 8 + (tid >> 3);
    const int a    = blockIdx.x;               // 0..128
    const int z    = blockIdx.z;

    float theta = angles[a];
    float sn, cs;
    sincosf(theta, &sn, &cs);

    float Rs, Rt, Cs, Ct;
    const char* bimg;
    if (fabsf(cs) >= fabsf(sn)) { Rs = sn; Rt = cs;  Cs = cs; Ct = -sn; bimg = TP; }
    else                        { Rs = cs; Rt = -sn; Cs = sn; Ct = cs;  bimg = TPT; }

    const float s_c = (float)s - 127.5f;
    const float pr0 = fmaf(s_c, Rs, 180.5f) - 127.5f * Rt;
    const float pc0 = fmaf(s_c, Cs, 180.5f) - 127.5f * Ct;

    // Work-skip clip: nonzero bilinear only for padded coords in [52, 309].
    const float LO = 52.0f, HI = 309.0f;
    float tmin = 0.0f, tmax = 255.0f;
    {
        float inv = 1.0f / Rt;
        float ta = (LO - pr0) * inv, tb = (HI - pr0) * inv;
        tmin = fmaxf(tmin, fminf(ta, tb));
        tmax = fminf(tmax, fmaxf(ta, tb));
    }
    if (fabsf(Ct) > 1e-6f) {
        float inv = 1.0f / Ct;
        float ta = (LO - pc0) * inv, tb = (HI - pc0) * inv;
        tmin = fmaxf(tmin, fminf(ta, tb));
        tmax = fminf(tmax, fmaxf(ta, tb));
    } else if (!(pc0 >= LO && pc0 <= HI)) {
        tmax = -1.0f;
    }

    // lane t = z*128 + tpar + 2*i, i in [0,64); chunks of 16 i (slop-safe pad).
    const float tb0 = (float)(z * 128 + tpar);
    int i0 = (int)ceilf((tmin - tb0) * 0.5f);
    int i1 = (int)floorf((tmax - tb0) * 0.5f);
    i0 = max(i0, 0);
    i1 = min(i1, 63);
    int c0 = i0 >> 4, c1 = i1 >> 4;
    if (i1 < i0) { c0 = 1; c1 = 0; }

    const int dr = tap >> 1, dc = tap & 1;
    const unsigned tapoff = (unsigned)(dr * ROWB + dc * TEXB);
    const float xb = dc ? 0.0f : 1.0f, xs = dc ? 1.0f : -1.0f;
    const float yb = dr ? 0.0f : 1.0f, ys = dr ? 1.0f : -1.0f;

    float a0=0.f,a1=0.f,a2=0.f,a3=0.f,a4=0.f,a5=0.f,a6=0.f,a7=0.f;       // norm
    float b0=0.f,b1=0.f,b2=0.f,b3=0.f,b4=0.f,b5=0.f,b6=0.f,b7=0.f;       // flip

    for (int c = c0; c <= c1; ++c) {
        h2 n0={},n1={},n2={},n3={}, f0={},f1={},f2={},f3={};
        float tf = fmaf(32.0f, (float)c, tb0);
        #pragma unroll
        for (int k = 0; k < 16; ++k) {
            float ppr = fmaf(tf, Rt, pr0);
            float ppc = fmaf(tf, Ct, pc0);
            tf += 2.0f;
            float wy, wx;
            int ir, ic;
            asm("v_fract_f32 %0, %1"       : "=v"(wy) : "v"(ppr));
            asm("v_fract_f32 %0, %1"       : "=v"(wx) : "v"(ppc));
            asm("v_cvt_flr_i32_f32 %0, %1" : "=v"(ir) : "v"(ppr));
            asm("v_cvt_flr_i32_f32 %0, %1" : "=v"(ic) : "v"(ppc));
            unsigned x = ((unsigned)ic << 5) + tapoff;
            unsigned bo;
            asm("v_mad_u32_u24 %0, %1, %2, %3"
                : "=v"(bo) : "v"(ir), "s"(ROWB), "v"(x));
            float w = fmaf(xs, wx, xb) * fmaf(ys, wy, yb);
            auto pkr = __builtin_amdgcn_cvt_pkrtz(w, w);
            h2 wv = __builtin_bit_cast(h2, pkr);
            uint4 qn = *(const uint4*)(bimg + bo);
            uint4 qf = *(const uint4*)(bimg + bo + 16);
            n0 = wv * u2h(qn.x) + n0;
            n1 = wv * u2h(qn.y) + n1;
            n2 = wv * u2h(qn.z) + n2;
            n3 = wv * u2h(qn.w) + n3;
            f0 = wv * u2h(qf.x) + f0;
            f1 = wv * u2h(qf.y) + f1;
            f2 = wv * u2h(qf.z) + f2;
            f3 = wv * u2h(qf.w) + f3;
        }
        a0 += (float)n0.x; a1 += (float)n0.y; a2 += (float)n1.x; a3 += (float)n1.y;
        a4 += (float)n2.x; a5 += (float)n2.y; a6 += (float)n3.x; a7 += (float)n3.y;
        b0 += (float)f0.x; b1 += (float)f0.y; b2 += (float)f1.x; b3 += (float)f1.y;
        b4 += (float)f2.x; b5 += (float)f2.y; b6 += (float)f3.x; b7 += (float)f3.y;
    }

    // Reduce taps (bits 0-1) and t-parity (bit 2).
    #define RED(x) { x += __shfl_xor(x, 1); x += __shfl_xor(x, 2); x += __shfl_xor(x, 4); }
    RED(a0) RED(a1) RED(a2) RED(a3) RED(a4) RED(a5) RED(a6) RED(a7)
    RED(b0) RED(b1) RED(b2) RED(b3) RED(b4) RED(b5) RED(b6) RED(b7)
    #undef RED

    if ((tid & 7) == 0) {
        const size_t AR = (size_t)N_ANGLES * RES;
        const size_t zb = (size_t)z * BATCH * AR;
        size_t pbase = zb + (size_t)a * RES + s;             // primary angle i
        part[pbase         ] = __float2half(a0);
        part[pbase + 1 * AR] = __float2half(a1);
        part[pbase + 2 * AR] = __float2half(a2);
        part[pbase + 3 * AR] = __float2half(a3);
        part[pbase + 4 * AR] = __float2half(a4);
        part[pbase + 5 * AR] = __float2half(a5);
        part[pbase + 6 * AR] = __float2half(a6);
        part[pbase + 7 * AR] = __float2half(a7);
        if (a != 0) {                                        // partner 256-i
            size_t qbase = zb + (size_t)(N_ANGLES - a) * RES + s;
            part[qbase         ] = __float2half(b0);
            part[qbase + 1 * AR] = __float2half(b1);
            part[qbase + 2 * AR] = __float2half(b2);
            part[qbase + 3 * AR] = __float2half(b3);
            part[qbase + 4 * AR] = __float2half(b4);
            part[qbase + 5 * AR] = __float2half(b5);
            part[qbase + 6 * AR] = __float2half(b6);
            part[qbase + 7 * AR] = __float2half(b7);
        }
    }
}

__global__ void combine(const __half2* __restrict__ p, float2* __restrict__ out) {
    const int n2 = BATCH * N_ANGLES * RES / 2;   // 262144
    int i = blockIdx.x * blockDim.x + threadIdx.x;
    if (i < n2) {
        float2 x = __half22float2(p[i]);
        float2 y = __half22float2(p[i + n2]);
        out[i] = make_float2(x.x + y.x, x.y + y.y);
    }
}

extern "C" void kernel_launch(void* const* d_in, const int* in_sizes, int n_in,
                              void* d_out, int out_size, void* d_ws, size_t ws_size,
                              hipStream_t stream) {
    const float* imgs   = (const float*)d_in[0];
    const float* angles = (const float*)d_in[1];
    float* out = (float*)d_out;

    const size_t texBytes = (size_t)TPAD * TPAD * TEXB;      // 4.24 MB
    char*  TP   = (char*)d_ws;
    char*  TPT  = TP + texBytes;
    __half* part = (__half*)(TPT + texBytes);                // 2 x 1MB fp16

    const int prep_total = 2 * TPAD * TPAD * 8;
    prep_pack<<<(prep_total + 255) / 256, 256, 0, stream>>>(
        imgs, (unsigned int*)TP, (unsigned int*)TPT);

    dim3 grid(NA2, 32, 2);                                   // 8256 x 64 thr
    radon_kernel<<<grid, 64, 0, stream>>>(TP, TPT, angles, part);

    const int n2 = BATCH * N_ANGLES * RES / 2;
    combine<<<(n2 + 255) / 256, 256, 0, stream>>>((const __half2*)part, (float2*)out);
}

// Round 9
// 62.247 us; speedup vs baseline: 1.2246x; 1.2246x over previous
//
#include <hip/hip_runtime.h>
#include <hip/hip_fp16.h>
#include <math.h>

#define RES 256
#define TPAD 364              // padded texture dim: image coords -53..310
#define N_ANGLES 256
#define NA2 129               // paired angle slots: i and 256-i
#define BATCH 8
#define ROWB (TPAD * 16)      // plane row pitch in bytes (5824)

typedef _Float16 h2 __attribute__((ext_vector_type(2)));
__device__ inline h2 u2h(unsigned u) { return __builtin_bit_cast(h2, u); }

// Four planes of 16B texels (8 x fp16 per texel), each TPAD x TPAD, zero
// outside image:
//   plane 0: normal orientation, image            plane 1: normal, x-flipped
//   plane 2: transposed,        image             plane 3: transposed, x-flipped
__global__ void prep_pack(const float* __restrict__ imgs,
                          unsigned int* __restrict__ W) {
    int idx = blockIdx.x * blockDim.x + threadIdx.x;
    const int total = 4 * TPAD * TPAD * 4;      // plane x pixel x batch-pair
    if (idx >= total) return;
    int pair  = idx & 3;
    int px    = (idx >> 2) % (TPAD * TPAD);
    int plane = (idx >> 2) / (TPAD * TPAD);
    int orient = plane >> 1, side = plane & 1;
    int ct = px % TPAD, rt = px / TPAD;
    int ri = rt - 53, ci = ct - 53;
    int row, col;
    if (orient == 0) { row = ri; col = side ? (255 - ci) : ci; }
    else             { row = ci; col = side ? (255 - ri) : ri; }
    float v0 = 0.0f, v1 = 0.0f;
    if ((unsigned)row < RES && (unsigned)col < RES) {
        const float* p = imgs + ((size_t)(pair * 2) * RES + row) * RES + col;
        v0 = p[0];
        v1 = p[RES * RES];
    }
    __half2 h = __halves2half2(__float2half_rn(v0), __float2half_rn(v1));
    W[((size_t)plane * TPAD * TPAD + px) * 4 + pair] =
        *reinterpret_cast<unsigned int*>(&h);
}

// 128-thread blocks (2 waves). Lane = tap(2b) | tpar(1b) | s(3b); wave = s-octet.
// grid (129 angles, 16 s-blocks, 2 z). Each step: ONE addr/weight computation
// serves angle i (norm plane) and angle 256-i (flip plane) x 8 batches.
__global__ __launch_bounds__(128) void radon_kernel(
        const char* __restrict__ TEX,
        const float* __restrict__ angles,
        __half* __restrict__ part) {
    const int tid  = threadIdx.x;
    const int tap  = tid & 3;
    const int tpar = (tid >> 2) & 1;
    const int s    = blockIdx.y * 16 + (tid >> 3);
    const int a    = blockIdx.x;               // 0..128
    const int z    = blockIdx.z;

    float theta = angles[a];
    float sn, cs;
    sincosf(theta, &sn, &cs);

    const size_t planeB = (size_t)TPAD * TPAD * 16;
    float Rs, Rt, Cs, Ct;
    const char* bN;
    const char* bF;
    if (fabsf(cs) >= fabsf(sn)) {
        Rs = sn; Rt = cs;  Cs = cs; Ct = -sn;
        bN = TEX;              bF = TEX + planeB;
    } else {
        Rs = cs; Rt = -sn; Cs = sn; Ct = cs;
        bN = TEX + 2 * planeB; bF = TEX + 3 * planeB;
    }

    const float s_c = (float)s - 127.5f;
    const float pr0 = fmaf(s_c, Rs, 180.5f) - 127.5f * Rt;
    const float pc0 = fmaf(s_c, Cs, 180.5f) - 127.5f * Ct;

    // Work-skip clip: nonzero bilinear only for padded coords in [52, 309].
    const float LO = 52.0f, HI = 309.0f;
    float tmin = 0.0f, tmax = 255.0f;
    {
        float inv = 1.0f / Rt;
        float ta = (LO - pr0) * inv, tb = (HI - pr0) * inv;
        tmin = fmaxf(tmin, fminf(ta, tb));
        tmax = fminf(tmax, fmaxf(ta, tb));
    }
    if (fabsf(Ct) > 1e-6f) {
        float inv = 1.0f / Ct;
        float ta = (LO - pc0) * inv, tb = (HI - pc0) * inv;
        tmin = fmaxf(tmin, fminf(ta, tb));
        tmax = fminf(tmax, fmaxf(ta, tb));
    } else if (!(pc0 >= LO && pc0 <= HI)) {
        tmax = -1.0f;
    }

    // lane t = z*128 + tpar + 2*i, i in [0,64); chunks of 16.
    const float tb0 = (float)(z * 128 + tpar);
    int i0 = (int)ceilf((tmin - tb0) * 0.5f);
    int i1 = (int)floorf((tmax - tb0) * 0.5f);
    i0 = max(i0, 0);
    i1 = min(i1, 63);
    int c0 = i0 >> 4, c1 = i1 >> 4;
    if (i1 < i0) { c0 = 1; c1 = 0; }

    const int dr = tap >> 1, dc = tap & 1;
    const unsigned tapoff = (unsigned)(dr * ROWB + dc * 16);
    const float xb = dc ? 0.0f : 1.0f, xs = dc ? 1.0f : -1.0f;
    const float yb = dr ? 0.0f : 1.0f, ys = dr ? 1.0f : -1.0f;

    float a0=0.f,a1=0.f,a2=0.f,a3=0.f,a4=0.f,a5=0.f,a6=0.f,a7=0.f;   // norm
    float b0=0.f,b1=0.f,b2=0.f,b3=0.f,b4=0.f,b5=0.f,b6=0.f,b7=0.f;   // flip

    for (int c = c0; c <= c1; ++c) {
        h2 n0={},n1={},n2={},n3={}, f0={},f1={},f2={},f3={};
        float tf = fmaf(32.0f, (float)c, tb0);
        #pragma unroll
        for (int k = 0; k < 16; ++k) {
            float ppr = fmaf(tf, Rt, pr0);
            float ppc = fmaf(tf, Ct, pc0);
            tf += 2.0f;
            float wy, wx;
            int ir, ic;
            asm("v_fract_f32 %0, %1"       : "=v"(wy) : "v"(ppr));
            asm("v_fract_f32 %0, %1"       : "=v"(wx) : "v"(ppc));
            asm("v_cvt_flr_i32_f32 %0, %1" : "=v"(ir) : "v"(ppr));
            asm("v_cvt_flr_i32_f32 %0, %1" : "=v"(ic) : "v"(ppc));
            unsigned x = ((unsigned)ic << 4) + tapoff;
            unsigned bo;
            asm("v_mad_u32_u24 %0, %1, %2, %3"
                : "=v"(bo) : "v"(ir), "s"(ROWB), "v"(x));
            float w = fmaf(xs, wx, xb) * fmaf(ys, wy, yb);
            auto pkr = __builtin_amdgcn_cvt_pkrtz(w, w);
            h2 wv = __builtin_bit_cast(h2, pkr);
            uint4 qn = *(const uint4*)(bN + bo);   // shared boff, two SGPR bases
            uint4 qf = *(const uint4*)(bF + bo);
            n0 = wv * u2h(qn.x) + n0;
            n1 = wv * u2h(qn.y) + n1;
            n2 = wv * u2h(qn.z) + n2;
            n3 = wv * u2h(qn.w) + n3;
            f0 = wv * u2h(qf.x) + f0;
            f1 = wv * u2h(qf.y) + f1;
            f2 = wv * u2h(qf.z) + f2;
            f3 = wv * u2h(qf.w) + f3;
        }
        a0 += (float)n0.x; a1 += (float)n0.y; a2 += (float)n1.x; a3 += (float)n1.y;
        a4 += (float)n2.x; a5 += (float)n2.y; a6 += (float)n3.x; a7 += (float)n3.y;
        b0 += (float)f0.x; b1 += (float)f0.y; b2 += (float)f1.x; b3 += (float)f1.y;
        b4 += (float)f2.x; b5 += (float)f2.y; b6 += (float)f3.x; b7 += (float)f3.y;
    }

    // Reduce taps (bits 0-1) and t-parity (bit 2) — in-wave only.
    #define RED(x) { x += __shfl_xor(x, 1); x += __shfl_xor(x, 2); x += __shfl_xor(x, 4); }
    RED(a0) RED(a1) RED(a2) RED(a3) RED(a4) RED(a5) RED(a6) RED(a7)
    RED(b0) RED(b1) RED(b2) RED(b3) RED(b4) RED(b5) RED(b6) RED(b7)
    #undef RED

    if ((tid & 7) == 0) {
        const size_t AR = (size_t)N_ANGLES * RES;
        const size_t zb = (size_t)z * BATCH * AR;
        size_t pbase = zb + (size_t)a * RES + s;             // primary angle i
        part[pbase         ] = __float2half(a0);
        part[pbase + 1 * AR] = __float2half(a1);
        part[pbase + 2 * AR] = __float2half(a2);
        part[pbase + 3 * AR] = __float2half(a3);
        part[pbase + 4 * AR] = __float2half(a4);
        part[pbase + 5 * AR] = __float2half(a5);
        part[pbase + 6 * AR] = __float2half(a6);
        part[pbase + 7 * AR] = __float2half(a7);
        if (a != 0) {                                        // partner 256-i
            size_t qbase = zb + (size_t)(N_ANGLES - a) * RES + s;
            part[qbase         ] = __float2half(b0);
            part[qbase + 1 * AR] = __float2half(b1);
            part[qbase + 2 * AR] = __float2half(b2);
            part[qbase + 3 * AR] = __float2half(b3);
            part[qbase + 4 * AR] = __float2half(b4);
            part[qbase + 5 * AR] = __float2half(b5);
            part[qbase + 6 * AR] = __float2half(b6);
            part[qbase + 7 * AR] = __float2half(b7);
        }
    }
}

__global__ void combine(const __half2* __restrict__ p, float2* __restrict__ out) {
    const int n2 = BATCH * N_ANGLES * RES / 2;   // 262144
    int i = blockIdx.x * blockDim.x + threadIdx.x;
    if (i < n2) {
        float2 x = __half22float2(p[i]);
        float2 y = __half22float2(p[i + n2]);
        out[i] = make_float2(x.x + y.x, x.y + y.y);
    }
}

extern "C" void kernel_launch(void* const* d_in, const int* in_sizes, int n_in,
                              void* d_out, int out_size, void* d_ws, size_t ws_size,
                              hipStream_t stream) {
    const float* imgs   = (const float*)d_in[0];
    const float* angles = (const float*)d_in[1];
    float* out = (float*)d_out;

    const size_t planeB = (size_t)TPAD * TPAD * 16;          // 2.12 MB
    char*   TEX  = (char*)d_ws;                              // 4 planes, 8.48 MB
    __half* part = (__half*)(TEX + 4 * planeB);              // 2 x 1 MB fp16

    const int prep_total = 4 * TPAD * TPAD * 4;
    prep_pack<<<(prep_total + 255) / 256, 256, 0, stream>>>(
        imgs, (unsigned int*)TEX);

    dim3 grid(NA2, 16, 2);                                   // 4128 x 128 thr
    radon_kernel<<<grid, 128, 0, stream>>>(TEX, angles, part);

    const int n2 = BATCH * N_ANGLES * RES / 2;
    combine<<<(n2 + 255) / 256, 256, 0, stream>>>((const __half2*)part, (float2*)out);
}